// Round 2
// baseline (191.476 us; speedup 1.0000x reference)
//
#include <hip/hip_runtime.h>
#include <hip/hip_cooperative_groups.h>

namespace cg = cooperative_groups;

#define NA 2048
#define NT 256
#define NB 256
#define TI 8    // atoms per block

__device__ __forceinline__ float silu_f(float x) {
    return x / (1.0f + __expf(-x));
}

__global__ __launch_bounds__(NT) void les_fused(
    const float* __restrict__ pos,
    const float* __restrict__ cw1, const float* __restrict__ cb1,
    const float* __restrict__ cw2, const float* __restrict__ cb2,
    const float* __restrict__ cw3, const float* __restrict__ cb3,
    const float* __restrict__ ew1, const float* __restrict__ eb1,
    const float* __restrict__ ew2, const float* __restrict__ eb2,
    const float* __restrict__ ew3, const float* __restrict__ eb3,
    float* __restrict__ out,
    float* __restrict__ rawq,
    float* __restrict__ blockQ,
    float* __restrict__ blockEsr,
    float* __restrict__ blockElr)
{
    cg::grid_group grid = cg::this_grid();

    __shared__ float spx[NA], spy[NA], spz[NA];   // 24 KB, lives across phases
    __shared__ float sq[NA];                      // 8 KB, phase-2 charges
    __shared__ float sfeat[TI][16];
    __shared__ float sh1[4][64];
    __shared__ float rq8[TI], esr8[TI], el8[TI];
    __shared__ float sred[4];

    const int b    = blockIdx.x;
    const int tid  = threadIdx.x;
    const int lane = tid & 63;
    const int wv   = tid >> 6;

    // ---- stage positions (SoA) ----
    for (int j = tid; j < NA; j += NT) {
        spx[j] = pos[3*j + 0];
        spy[j] = pos[3*j + 1];
        spz[j] = pos[3*j + 2];
    }
    __syncthreads();

    // ---- phase 1: RBF features, 2 atoms per wave ----
    #pragma unroll
    for (int a = 0; a < 2; ++a) {
        const int i = b * TI + wv * 2 + a;
        const float pix = spx[i], piy = spy[i], piz = spz[i];
        float acc[16];
        #pragma unroll
        for (int r = 0; r < 16; ++r) acc[r] = 0.0f;
        for (int j = lane; j < NA; j += 64) {
            float dx = pix - spx[j];
            float dy = piy - spy[j];
            float dz = piz - spz[j];
            float d2 = dx*dx + dy*dy + dz*dz;
            if (d2 > 0.0f && d2 < 25.0f) {
                float d  = sqrtf(d2);
                float sm = 0.5f * (1.0f + __cosf(0.6283185307179586f * d)); // cos(pi*d/5)
                #pragma unroll
                for (int r = 0; r < 16; ++r) {
                    float c = 0.5f + 0.3f * (float)r;      // linspace(0.5, 5, 16)
                    float t = d - c;
                    acc[r] += sm * __expf(-t * t * 25.28395061728395f); // 1/(2*eta^2)
                }
            }
        }
        #pragma unroll
        for (int r = 0; r < 16; ++r) {
            float v = acc[r];
            #pragma unroll
            for (int off = 32; off > 0; off >>= 1) v += __shfl_down(v, off, 64);
            if (lane == 0) sfeat[wv*2 + a][r] = v;
        }
    }
    __syncthreads();

    // ---- phase 1b: both MLPs, 4 wave-tasks per wave (task = atom*2 + which) ----
    for (int k = 0; k < 4; ++k) {
        const int t     = wv * 4 + k;
        const int a     = t >> 1;        // local atom 0..7 (wave-local: 2*wv + (k>>1))
        const int which = t & 1;         // 0: charge MLP, 1: energy MLP

        const float* w1 = which ? ew1 : cw1;
        const float* b1 = which ? eb1 : cb1;
        const float* w2 = which ? ew2 : cw2;
        const float* b2 = which ? eb2 : cb2;
        const float* w3 = which ? ew3 : cw3;
        const float* b3 = which ? eb3 : cb3;

        float s = b1[lane];
        #pragma unroll
        for (int r = 0; r < 16; ++r)
            s += sfeat[a][r] * w1[r * 64 + lane];
        sh1[wv][lane] = silu_f(s);
        __syncthreads();

        float s2 = b2[lane];
        #pragma unroll 8
        for (int k2 = 0; k2 < 64; ++k2)
            s2 += sh1[wv][k2] * w2[k2 * 64 + lane];
        float h2 = silu_f(s2);

        float p = h2 * w3[lane];
        #pragma unroll
        for (int off = 32; off > 0; off >>= 1) p += __shfl_down(p, off, 64);

        if (lane == 0) {
            float o = p + b3[0];
            if (which == 0) { rq8[a] = o; rawq[b * TI + a] = o; }
            else            { esr8[a] = o; }
        }
        __syncthreads();
    }
    if (tid == 0) {
        float q = 0.0f, e = 0.0f;
        #pragma unroll
        for (int r = 0; r < TI; ++r) { q += rq8[r]; e += esr8[r]; }
        blockQ[b]   = q;
        blockEsr[b] = e;
    }

    grid.sync();

    // ---- phase 2: charge correction + E_lr rows (positions still in LDS) ----
    {
        float v = blockQ[tid];           // NT == NB == 256
        #pragma unroll
        for (int off = 32; off > 0; off >>= 1) v += __shfl_down(v, off, 64);
        if (lane == 0) sred[wv] = v;
    }
    __syncthreads();
    const float corr = -(sred[0] + sred[1] + sred[2] + sred[3]) * (1.0f / (float)NA);

    for (int j = tid; j < NA; j += NT) sq[j] = rawq[j] + corr;
    __syncthreads();

    #pragma unroll
    for (int a = 0; a < 2; ++a) {
        const int i = b * TI + wv * 2 + a;
        const float pix = spx[i], piy = spy[i], piz = spz[i];
        float s = 0.0f;
        for (int j = lane; j < NA; j += 64) {
            float dx = pix - spx[j];
            float dy = piy - spy[j];
            float dz = piz - spz[j];
            float d2 = dx*dx + dy*dy + dz*dz;
            if (j != i) s += sq[j] * rsqrtf(d2);
        }
        #pragma unroll
        for (int off = 32; off > 0; off >>= 1) s += __shfl_down(s, off, 64);
        if (lane == 0) {
            el8[wv*2 + a] = sq[i] * s;
            out[1 + i]    = sq[i];       // charges output
        }
    }
    __syncthreads();
    if (tid == 0) {
        float e = 0.0f;
        #pragma unroll
        for (int r = 0; r < TI; ++r) e += el8[r];
        blockElr[b] = e;
    }

    grid.sync();

    // ---- phase 3: block 0 reduces the 256 per-block partials ----
    if (b == 0) {
        float velr = blockElr[tid];
        float vesr = blockEsr[tid];
        #pragma unroll
        for (int off = 32; off > 0; off >>= 1) {
            velr += __shfl_down(velr, off, 64);
            vesr += __shfl_down(vesr, off, 64);
        }
        __syncthreads();   // sred reuse hazard vs phase 2
        if (lane == 0) { sred[wv] = velr; sfeat[0][wv] = vesr; }
        __syncthreads();
        if (tid == 0) {
            float elr = sred[0] + sred[1] + sred[2] + sred[3];
            float esr = sfeat[0][0] + sfeat[0][1] + sfeat[0][2] + sfeat[0][3];
            out[0] = 0.5f * elr + esr;
        }
    }
}

extern "C" void kernel_launch(void* const* d_in, const int* in_sizes, int n_in,
                              void* d_out, int out_size, void* d_ws, size_t ws_size,
                              hipStream_t stream) {
    const float* pos = (const float*)d_in[0];
    const float* cw1 = (const float*)d_in[1];
    const float* cb1 = (const float*)d_in[2];
    const float* cw2 = (const float*)d_in[3];
    const float* cb2 = (const float*)d_in[4];
    const float* cw3 = (const float*)d_in[5];
    const float* cb3 = (const float*)d_in[6];
    const float* ew1 = (const float*)d_in[7];
    const float* eb1 = (const float*)d_in[8];
    const float* ew2 = (const float*)d_in[9];
    const float* eb2 = (const float*)d_in[10];
    const float* ew3 = (const float*)d_in[11];
    const float* eb3 = (const float*)d_in[12];
    float* out = (float*)d_out;

    float* rawq     = (float*)d_ws;        // 2048
    float* blockQ   = rawq + NA;           // 256
    float* blockEsr = blockQ + NB;         // 256
    float* blockElr = blockEsr + NB;       // 256

    void* args[] = {
        (void*)&pos,
        (void*)&cw1, (void*)&cb1, (void*)&cw2, (void*)&cb2, (void*)&cw3, (void*)&cb3,
        (void*)&ew1, (void*)&eb1, (void*)&ew2, (void*)&eb2, (void*)&ew3, (void*)&eb3,
        (void*)&out, (void*)&rawq, (void*)&blockQ, (void*)&blockEsr, (void*)&blockElr
    };
    hipLaunchCooperativeKernel((const void*)les_fused, dim3(NB), dim3(NT), args, 0, stream);
}

// Round 3
// 104.769 us; speedup vs baseline: 1.8276x; 1.8276x over previous
//
#include <hip/hip_runtime.h>

#define NA 2048
#define NT 256

__device__ __forceinline__ float silu_f(float x) { return x / (1.0f + __expf(-x)); }

__device__ __forceinline__ float wave_reduce(float v) {
    #pragma unroll
    for (int off = 32; off > 0; off >>= 1) v += __shfl_down(v, off, 64);
    return v;
}

// ---------------------------------------------------------------------------
// k1: RBF features + both MLPs for atom i = blockIdx.x.
// 2048 blocks x 256 threads -> 8 blocks/CU, full latency hiding.
// Writes rawq[i], esr[i], pxyzq[i] = (x,y,z,rawq).
// ---------------------------------------------------------------------------
__global__ __launch_bounds__(NT) void k1_feat_mlp(
    const float* __restrict__ pos,
    const float* __restrict__ cw1, const float* __restrict__ cb1,
    const float* __restrict__ cw2, const float* __restrict__ cb2,
    const float* __restrict__ cw3, const float* __restrict__ cb3,
    const float* __restrict__ ew1, const float* __restrict__ eb1,
    const float* __restrict__ ew2, const float* __restrict__ eb2,
    const float* __restrict__ ew3, const float* __restrict__ eb3,
    float4* __restrict__ pxyzq, float* __restrict__ rawq, float* __restrict__ esr)
{
    __shared__ float wsum[4][16];
    __shared__ float sfeat[16];
    __shared__ float sh1[4][64];
    const int i = blockIdx.x;
    const int tid = threadIdx.x, lane = tid & 63, wv = tid >> 6;
    const float pix = pos[3*i], piy = pos[3*i+1], piz = pos[3*i+2];

    float acc[16];
    #pragma unroll
    for (int r = 0; r < 16; ++r) acc[r] = 0.0f;

    for (int j = tid; j < NA; j += NT) {
        float dx = pix - pos[3*j], dy = piy - pos[3*j+1], dz = piz - pos[3*j+2];
        float d2 = dx*dx + dy*dy + dz*dz;
        if (d2 > 0.0f && d2 < 25.0f) {
            float d  = sqrtf(d2);
            float sm = 0.5f * (1.0f + __cosf(0.6283185307179586f * d)); // cos(pi*d/5)
            #pragma unroll
            for (int r = 0; r < 16; ++r) {
                float t = d - (0.5f + 0.3f * (float)r);   // centers linspace(0.5,5,16)
                acc[r] += sm * __expf(-t * t * 25.28395061728395f); // 1/(2*eta^2)
            }
        }
    }
    #pragma unroll
    for (int r = 0; r < 16; ++r) {
        float v = wave_reduce(acc[r]);
        if (lane == 0) wsum[wv][r] = v;
    }
    __syncthreads();
    if (tid < 16) sfeat[tid] = wsum[0][tid] + wsum[1][tid] + wsum[2][tid] + wsum[3][tid];
    __syncthreads();

    // Both MLPs: waves 0,1 are the real tasks; waves 2,3 duplicate (so the
    // barrier between layer-1 write and layer-2 read is non-divergent).
    const int which = wv & 1;   // 0: charge MLP, 1: energy MLP
    const float* w1 = which ? ew1 : cw1;
    const float* b1 = which ? eb1 : cb1;
    const float* w2 = which ? ew2 : cw2;
    const float* b2 = which ? eb2 : cb2;
    const float* w3 = which ? ew3 : cw3;
    const float* b3 = which ? eb3 : cb3;

    float s = b1[lane];
    #pragma unroll
    for (int r = 0; r < 16; ++r) s += sfeat[r] * w1[r * 64 + lane];
    sh1[wv][lane] = silu_f(s);
    __syncthreads();

    float s2 = b2[lane];
    #pragma unroll 8
    for (int k = 0; k < 64; ++k) s2 += sh1[wv][k] * w2[k * 64 + lane];
    float p = silu_f(s2) * w3[lane];
    p = wave_reduce(p);

    if (lane == 0 && wv < 2) {
        float o = p + b3[0];
        if (wv == 0) { rawq[i] = o; pxyzq[i] = make_float4(pix, piy, piz, o); }
        else         { esr[i] = o; }
    }
}

// ---------------------------------------------------------------------------
// k2: pair pass with RAW charges. s_i = sum' qr_j/r_ij, t_i = sum' 1/r_ij.
// One block per atom, coalesced float4 loads (L2-resident), no LDS staging.
// ---------------------------------------------------------------------------
__global__ __launch_bounds__(NT) void k2_pair(const float4* __restrict__ pxyzq,
                                              float* __restrict__ sarr,
                                              float* __restrict__ tarr)
{
    __shared__ float ws[4][2];
    const int i = blockIdx.x, tid = threadIdx.x, lane = tid & 63, wv = tid >> 6;
    const float4 pi = pxyzq[i];
    float s = 0.0f, t = 0.0f;
    for (int j = tid; j < NA; j += NT) {
        float4 pj = pxyzq[j];
        float dx = pi.x - pj.x, dy = pi.y - pj.y, dz = pi.z - pj.z;
        float d2 = dx*dx + dy*dy + dz*dz;
        if (j != i) {
            float rinv = rsqrtf(d2);
            t += rinv;
            s += pj.w * rinv;
        }
    }
    s = wave_reduce(s);
    t = wave_reduce(t);
    if (lane == 0) { ws[wv][0] = s; ws[wv][1] = t; }
    __syncthreads();
    if (tid == 0) {
        sarr[i] = ws[0][0] + ws[1][0] + ws[2][0] + ws[3][0];
        tarr[i] = ws[0][1] + ws[1][1] + ws[2][1] + ws[3][1];
    }
}

// ---------------------------------------------------------------------------
// k3: final reduction + correction + outputs.
// E_lr = 0.5*(S_qq + c*(A + B) + c^2*S_11), c = -sum(qr)/N
//   S_qq = sum qr_i s_i, A = sum qr_i t_i, B = sum s_i, S_11 = sum t_i
// ---------------------------------------------------------------------------
__global__ __launch_bounds__(NT) void k3_final(const float* __restrict__ rawq,
                                               const float* __restrict__ esr,
                                               const float* __restrict__ sarr,
                                               const float* __restrict__ tarr,
                                               float* __restrict__ out)
{
    __shared__ float wred[4][6];
    __shared__ float sc;
    const int tid = threadIdx.x, lane = tid & 63, wv = tid >> 6;
    float pq = 0, pe = 0, pqq = 0, pqt = 0, ps = 0, pt = 0;
    for (int i = tid; i < NA; i += NT) {
        float q = rawq[i], s = sarr[i], t = tarr[i];
        pq += q; pe += esr[i]; pqq += q * s; pqt += q * t; ps += s; pt += t;
    }
    pq  = wave_reduce(pq);  pe = wave_reduce(pe);  pqq = wave_reduce(pqq);
    pqt = wave_reduce(pqt); ps = wave_reduce(ps);  pt  = wave_reduce(pt);
    if (lane == 0) {
        wred[wv][0] = pq; wred[wv][1] = pe; wred[wv][2] = pqq;
        wred[wv][3] = pqt; wred[wv][4] = ps; wred[wv][5] = pt;
    }
    __syncthreads();
    if (tid == 0) {
        float q  = wred[0][0] + wred[1][0] + wred[2][0] + wred[3][0];
        float e  = wred[0][1] + wred[1][1] + wred[2][1] + wred[3][1];
        float qq = wred[0][2] + wred[1][2] + wred[2][2] + wred[3][2];
        float qt = wred[0][3] + wred[1][3] + wred[2][3] + wred[3][3];
        float ss = wred[0][4] + wred[1][4] + wred[2][4] + wred[3][4];
        float tt = wred[0][5] + wred[1][5] + wred[2][5] + wred[3][5];
        float c = -q * (1.0f / (float)NA);
        sc = c;
        out[0] = 0.5f * (qq + c * (qt + ss) + c * c * tt) + e;
    }
    __syncthreads();
    const float c = sc;
    for (int i = tid; i < NA; i += NT) out[1 + i] = rawq[i] + c;
}

extern "C" void kernel_launch(void* const* d_in, const int* in_sizes, int n_in,
                              void* d_out, int out_size, void* d_ws, size_t ws_size,
                              hipStream_t stream) {
    const float* pos = (const float*)d_in[0];
    const float* cw1 = (const float*)d_in[1];
    const float* cb1 = (const float*)d_in[2];
    const float* cw2 = (const float*)d_in[3];
    const float* cb2 = (const float*)d_in[4];
    const float* cw3 = (const float*)d_in[5];
    const float* cb3 = (const float*)d_in[6];
    const float* ew1 = (const float*)d_in[7];
    const float* eb1 = (const float*)d_in[8];
    const float* ew2 = (const float*)d_in[9];
    const float* eb2 = (const float*)d_in[10];
    const float* ew3 = (const float*)d_in[11];
    const float* eb3 = (const float*)d_in[12];
    float* out = (float*)d_out;

    // workspace layout (all written before read within one replay)
    float4* pxyzq = (float4*)d_ws;                  // 2048 float4
    float*  rawq  = (float*)(pxyzq + NA);           // 2048
    float*  esr   = rawq + NA;                      // 2048
    float*  sarr  = esr + NA;                       // 2048
    float*  tarr  = sarr + NA;                      // 2048

    k1_feat_mlp<<<NA, NT, 0, stream>>>(pos,
                                       cw1, cb1, cw2, cb2, cw3, cb3,
                                       ew1, eb1, ew2, eb2, ew3, eb3,
                                       pxyzq, rawq, esr);
    k2_pair<<<NA, NT, 0, stream>>>(pxyzq, sarr, tarr);
    k3_final<<<1, NT, 0, stream>>>(rawq, esr, sarr, tarr, out);
}